// Round 1
// baseline (724.898 us; speedup 1.0000x reference)
//
#include <hip/hip_runtime.h>

#define NUM_FIELDS 10
#define VOCAB 100000
#define EMBED_DIM 16
#define BATCH 16384
#define NPAIRS 45
#define ITEMS_PER_THREAD 4

// Native Clang vector type — accepted by __builtin_nontemporal_load/store
// (HIP_vector_type float4 is a struct and is rejected).
typedef float v4f __attribute__((ext_vector_type(4)));

// Packed (i | j<<8) for the 45 upper-triangle pairs, row-major (triu k=1 order).
__device__ __constant__ unsigned short PAIR_IJ[NPAIRS] = {
    0x0100, 0x0200, 0x0300, 0x0400, 0x0500, 0x0600, 0x0700, 0x0800, 0x0900,
    0x0201, 0x0301, 0x0401, 0x0501, 0x0601, 0x0701, 0x0801, 0x0901,
    0x0302, 0x0402, 0x0502, 0x0602, 0x0702, 0x0802, 0x0902,
    0x0403, 0x0503, 0x0603, 0x0703, 0x0803, 0x0903,
    0x0504, 0x0604, 0x0704, 0x0804, 0x0904,
    0x0605, 0x0705, 0x0805, 0x0905,
    0x0706, 0x0806, 0x0906,
    0x0807, 0x0907,
    0x0908
};

// One item = one output float4: item = ((b*45)+p)*4 + d4.
// 4 consecutive lanes (d4=0..3) read one contiguous 64B emb row -> single
// coalesced transaction; writes are flat-ordered -> fully coalesced.
//
// R0 change: gather loads are now CACHED (plain loads) instead of
// __builtin_nontemporal_load. emb is 640 MB vs 256 MB Infinity Cache; with
// normal allocation the uniform-random gather stream should see ~40% L3
// hits (each hit = one DRAM row activation avoided). Output stores remain
// non-temporal so the 47 MB write stream does not evict emb lines from L3.
__global__ __launch_bounds__(256) void ffm_pair_kernel(
        const int* __restrict__ x,
        const float* __restrict__ emb,
        float* __restrict__ out) {
    const int total  = BATCH * NPAIRS * 4;           // 2,949,120
    const int stride = total / ITEMS_PER_THREAD;     //   737,280
    const int tid0   = blockIdx.x * blockDim.x + threadIdx.x;
    if (tid0 >= stride) return;

    v4f a[ITEMS_PER_THREAD];
    v4f c[ITEMS_PER_THREAD];

    // Phase 1: compute addresses and issue ALL gather loads.
    #pragma unroll
    for (int k = 0; k < ITEMS_PER_THREAD; ++k) {
        const int tid = tid0 + k * stride;
        const int d4 = tid & 3;
        const int bp = tid >> 2;          // b*45 + p
        const int p  = bp % NPAIRS;
        const int b  = bp / NPAIRS;

        const unsigned int ij = PAIR_IJ[p];
        const int i = (int)(ij & 0xff);
        const int j = (int)(ij >> 8);

        const int xi = x[b * NUM_FIELDS + i] + i * VOCAB;
        const int xj = x[b * NUM_FIELDS + j] + j * VOCAB;

        const size_t rowA = ((size_t)j * (NUM_FIELDS * VOCAB) + (size_t)xi) * EMBED_DIM;
        const size_t rowB = ((size_t)i * (NUM_FIELDS * VOCAB) + (size_t)xj) * EMBED_DIM;

        a[k] = *(const v4f*)(emb + rowA + (size_t)d4 * 4);
        c[k] = *(const v4f*)(emb + rowB + (size_t)d4 * 4);
    }

    // Phase 2: multiply and store (streaming, nontemporal).
    #pragma unroll
    for (int k = 0; k < ITEMS_PER_THREAD; ++k) {
        const int tid = tid0 + k * stride;
        const v4f r = a[k] * c[k];
        __builtin_nontemporal_store(r, (v4f*)out + tid);
    }
}

extern "C" void kernel_launch(void* const* d_in, const int* in_sizes, int n_in,
                              void* d_out, int out_size, void* d_ws, size_t ws_size,
                              hipStream_t stream) {
    const int*   x   = (const int*)d_in[0];
    const float* emb = (const float*)d_in[1];
    float*       out = (float*)d_out;

    const int total  = BATCH * NPAIRS * 4;
    const int nthr   = total / ITEMS_PER_THREAD;     // 737,280
    const int block  = 256;
    const int grid   = (nthr + block - 1) / block;   // 2,880 blocks

    ffm_pair_kernel<<<grid, block, 0, stream>>>(x, emb, out);
}